// Round 22
// baseline (428.841 us; speedup 1.0000x reference)
//
#include <hip/hip_runtime.h>
#include <hip/hip_bf16.h>

#define DD 256      // feature dim
#define NM 64       // memory slots

typedef unsigned long long u64;
typedef float v2f __attribute__((ext_vector_type(2)));

struct v2x2 { v2f lo, hi; };
static __device__ __forceinline__ v2x2 splitf4(float4 f) {
    union { float4 a; v2x2 b; } u; u.a = f; return u.b;
}

// pk: acc(pair) += splat(src0 half) * c(pair).  Bit-identical to two fmaf.
#define PK_FMA_SPLATLO(acc, q2, c2) \
    asm("v_pk_fma_f32 %0, %1, %2, %0 op_sel:[0,0,0] op_sel_hi:[0,1,1]" \
        : "+v"(acc) : "v"(q2), "v"(c2))
#define PK_FMA_SPLATHI(acc, q2, c2) \
    asm("v_pk_fma_f32 %0, %1, %2, %0 op_sel:[1,0,0] op_sel_hi:[1,1,1]" \
        : "+v"(acc) : "v"(q2), "v"(c2))

// ---------------------------------------------------------------------------
// prep_tr: wt[d][o] = W[o][d] for Wq and Wk
// ---------------------------------------------------------------------------
__global__ __launch_bounds__(256) void prep_tr(
    const float* __restrict__ Wq, const float* __restrict__ Wk,
    float* __restrict__ wqt, float* __restrict__ wkt)
{
    const int o = blockIdx.x;
    const int d = threadIdx.x;
    if (blockIdx.y == 0) wqt[d * DD + o] = Wq[o * DD + d];
    else                 wkt[d * DD + o] = Wk[o * DD + d];
}

// ---------------------------------------------------------------------------
// prep_kT: kT4[(o>>2)*(NM*4) + n*4 + (o&3)] = k[n][o]   ([og][n][4] layout)
//   k[n][o] = sum_d mem[n][d]*Wk[o][d]  (fp32, d-ascending single-acc)
//   bias[n] = fl32(max(log(imp*0.99^age), -10))
// ---------------------------------------------------------------------------
__global__ __launch_bounds__(256) void prep_kT(
    const float* __restrict__ mem, const float* __restrict__ wkt,
    const float* __restrict__ imp, const float* __restrict__ age,
    float* __restrict__ kT4, float* __restrict__ bias)
{
    const int n = blockIdx.x;
    const int o = threadIdx.x;
    const float* mrow = mem + n * DD;
    float acc = 0.f;
    for (int d = 0; d < DD; ++d)
        acc = fmaf(mrow[d], wkt[d * DD + o], acc);
    kT4[(o >> 2) * (NM * 4) + n * 4 + (o & 3)] = acc;

    if (o == 0) {
        double eff = (double)imp[n] * pow(0.99, (double)age[n]);
        float b = (float)log(eff);
        if (!(b >= -10.0f)) b = -10.0f;
        bias[n] = b;
    }
}

// ---------------------------------------------------------------------------
// qgemm_s: q = query @ Wq^T, then raw biased scores -> out_attn (scratch).
// R22: 16 ROWS PER WAVE (128 thr, 2 waves, 32 rows, 48 KB LDS).
// DS-pipe model (m134 constants): at 8 rows/wave, per K-iter a wave issues
// 512 VALU-cyc of pk_fma but ~216 DS-cyc (16 uniform + 8 cw b128 + writes);
// 8 waves/CU -> DS 1728 vs VALU-wall 1024 = 1.7x oversubscribed -> the 60-69%
// VALUBusy plateau measured across 5 structures. cw reads are per-o-column
// (row-independent), so 16 rows/wave doubles pk per cw read: ratio -> 1.31.
// Chains: q d-ascending / scores o-ascending — bit-identical to R21
// (only lane<->(row,o) ownership moves).
// ---------------------------------------------------------------------------
#define ATHR 128
__global__ __launch_bounds__(ATHR, 2) void qgemm_s(
    const float* __restrict__ query,   // [M][DD]
    const float4* __restrict__ wqt4,   // [DD][NM]: wqt4[d*64+l] = WqT[d][4l..4l+3]
    const float4* __restrict__ kT44,   // [DD/4][NM]
    const float* __restrict__ bias,    // [NM]
    float* __restrict__ sout,          // [M][NM] (= out_attn, raw scores)
    int M)
{
    __shared__ float q_lds[32 * DD];        // 32 KB: query rows -> then q rows
    __shared__ float wq_lds[2][8 * 256];    // 16 KB dbuf: [d_local][o]

    const int t = threadIdx.x;              // 0..127
    const int l = t & 63;
    const int w = __builtin_amdgcn_readfirstlane((int)(t >> 6));  // 0..1
    const int row0 = blockIdx.x * 32;

    // stage 32 query rows (coalesced)
    {
        const float4* q4g = reinterpret_cast<const float4*>(query);
#pragma unroll
        for (int i = 0; i < 16; ++i) {
            const int idx = i * ATHR + t;          // 0..2047
            const int r = idx >> 6, c4 = idx & 63;
            int gr = row0 + r; if (gr > M - 1) gr = M - 1;
            *reinterpret_cast<float4*>(&q_lds[r * DD + c4 * 4]) =
                q4g[(size_t)gr * 64 + c4];
        }
    }
    // stage wqt chunk 0 (d = 0..7): 512 float4s, 4 per thread
    {
        float4* dst = reinterpret_cast<float4*>(wq_lds[0]);
#pragma unroll
        for (int j = 0; j < 4; ++j) dst[t + ATHR * j] = wqt4[t + ATHR * j];
    }
    __syncthreads();

    // ---- Phase A: q-GEMM (wave w rows 16w..16w+15; lane l: o = 4l..4l+3)
    v2f a01[16], a23[16];
#pragma unroll
    for (int rr = 0; rr < 16; ++rr) { a01[rr] = (v2f)(0.f); a23[rr] = (v2f)(0.f); }

    {
        const float* qbase = &q_lds[(w * 16) * DD];

        for (int c = 0; c < 32; ++c) {
            const int cn = (c + 1) & 31;
            float4 nx[4];
#pragma unroll
            for (int j = 0; j < 4; ++j) nx[j] = wqt4[cn * 512 + t + ATHR * j];

            {
                const float4* wb = reinterpret_cast<const float4*>(wq_lds[c & 1]);
                float4 cw[8];
#pragma unroll
                for (int i = 0; i < 8; ++i) cw[i] = wb[i * 64 + l];
                const v2x2 c0 = splitf4(cw[0]), c1 = splitf4(cw[1]);
                const v2x2 c2 = splitf4(cw[2]), c3 = splitf4(cw[3]);
                const v2x2 c4 = splitf4(cw[4]), c5 = splitf4(cw[5]);
                const v2x2 c6 = splitf4(cw[6]), c7 = splitf4(cw[7]);
#pragma unroll
                for (int rr = 0; rr < 16; ++rr) {
                    const float4 qqA = *reinterpret_cast<const float4*>(
                        qbase + rr * DD + c * 8);          // uniform ds_read_b128
                    const float4 qqB = *reinterpret_cast<const float4*>(
                        qbase + rr * DD + c * 8 + 4);
                    const v2x2 qA = splitf4(qqA);
                    const v2x2 qB = splitf4(qqB);
                    // d-ascending per chain (bit-identical):
                    PK_FMA_SPLATLO(a01[rr], qA.lo, c0.lo);   // d = 8c
                    PK_FMA_SPLATLO(a23[rr], qA.lo, c0.hi);
                    PK_FMA_SPLATHI(a01[rr], qA.lo, c1.lo);   // 8c+1
                    PK_FMA_SPLATHI(a23[rr], qA.lo, c1.hi);
                    PK_FMA_SPLATLO(a01[rr], qA.hi, c2.lo);   // 8c+2
                    PK_FMA_SPLATLO(a23[rr], qA.hi, c2.hi);
                    PK_FMA_SPLATHI(a01[rr], qA.hi, c3.lo);   // 8c+3
                    PK_FMA_SPLATHI(a23[rr], qA.hi, c3.hi);
                    PK_FMA_SPLATLO(a01[rr], qB.lo, c4.lo);   // 8c+4
                    PK_FMA_SPLATLO(a23[rr], qB.lo, c4.hi);
                    PK_FMA_SPLATHI(a01[rr], qB.lo, c5.lo);   // 8c+5
                    PK_FMA_SPLATHI(a23[rr], qB.lo, c5.hi);
                    PK_FMA_SPLATLO(a01[rr], qB.hi, c6.lo);   // 8c+6
                    PK_FMA_SPLATLO(a23[rr], qB.hi, c6.hi);
                    PK_FMA_SPLATHI(a01[rr], qB.hi, c7.lo);   // 8c+7
                    PK_FMA_SPLATHI(a23[rr], qB.hi, c7.hi);
                }
            }
            {
                float4* dst = reinterpret_cast<float4*>(wq_lds[(c + 1) & 1]);
#pragma unroll
                for (int j = 0; j < 4; ++j) dst[t + ATHR * j] = nx[j];
            }
            __syncthreads();
        }
    }

    // ---- write q into q_lds (query data dead after last iter's barrier)
#pragma unroll
    for (int rr = 0; rr < 16; ++rr) {
        const int lr = w * 16 + rr;
        float4 v; v.x = a01[rr].x; v.y = a01[rr].y; v.z = a23[rr].x; v.w = a23[rr].y;
        *reinterpret_cast<float4*>(&q_lds[lr * DD + 4 * l]) = v;
    }
    __syncthreads();

    // ---- Phase B: scores (lane = n; wave w rows 16w..16w+15)
    // Chain per (row,n): o-ascending fma — bit-identical to R21.
    {
        const int n = l;
        const float bn = bias[n];
        float sc[16];
#pragma unroll
        for (int r = 0; r < 16; ++r) sc[r] = 0.f;

        const float* qbase = &q_lds[(w * 16) * DD];
        for (int og = 0; og < DD / 4; ++og) {
            const float4 kt = kT44[og * NM + n];       // coalesced, L1-hot
#pragma unroll
            for (int r = 0; r < 16; ++r) {
                const float4 q4 = *reinterpret_cast<const float4*>(
                    qbase + r * DD + og * 4);          // uniform ds_read_b128
                float v = sc[r];
                v = fmaf(q4.x, kt.x, v);               // o-ascending chain
                v = fmaf(q4.y, kt.y, v);
                v = fmaf(q4.z, kt.z, v);
                v = fmaf(q4.w, kt.w, v);
                sc[r] = v;
            }
        }
#pragma unroll
        for (int r = 0; r < 16; ++r) {
            const int grow = row0 + w * 16 + r;
            if (grow < M) sout[(size_t)grow * NM + n] = sc[r] * 0.0625f + bn;
        }
    }
}

// ---------------------------------------------------------------------------
// fin3: raw scores (out_attn) -> topk (thread-per-row, 128 rows) -> final
// attn (overwrite out_attn, block-local) + retrieved (write out_ret fresh).
// Byte-identical to R19/R21's fin3.
// ---------------------------------------------------------------------------
#define FR 128    // rows per fin3 block
__global__ __launch_bounds__(256, 2) void fin3(
    const float* __restrict__ mem,     // [NM][DD]
    const int* __restrict__ topk_p,
    float* __restrict__ out_ret,       // [M][DD]
    float* __restrict__ out_attn,      // [M][NM] (raw scores in, attn out)
    int M)
{
    __shared__ float s_lds[FR * NM];   // 32 KB rotated scores
    __shared__ int   sel_i[FR * 16];   // 8 KB
    __shared__ float sel_w[FR * 16];   // 8 KB

    const int t = threadIdx.x;
    const int l = t & 63;
    const int w = __builtin_amdgcn_readfirstlane((int)(t >> 6));  // 0..3
    const int row0 = blockIdx.x * FR;
    const int k = *topk_p;

    // stage scores (coalesced read, rotated scatter: col c at (c+r)&63)
    {
#pragma unroll
        for (int i = 0; i < (FR * NM / 4) / 256; ++i) {    // 8 iters
            const int idx = i * 256 + t;                   // float4 index
            const int r = idx >> 4, c4 = idx & 15;
            int gr = row0 + r; if (gr > M - 1) gr = M - 1;
            const float4 v = *reinterpret_cast<const float4*>(
                &out_attn[(size_t)gr * NM + c4 * 4]);
            s_lds[r * NM + ((c4 * 4 + 0 + r) & 63)] = v.x;
            s_lds[r * NM + ((c4 * 4 + 1 + r) & 63)] = v.y;
            s_lds[r * NM + ((c4 * 4 + 2 + r) & 63)] = v.z;
            s_lds[r * NM + ((c4 * 4 + 3 + r) & 63)] = v.w;
        }
    }
    __syncthreads();

    // ---- per-row top-k: thread t handles row t (t < FR)
    if (t < FR) {
        const int r = t;
        float sv[NM];
#pragma unroll
        for (int n = 0; n < NM; ++n) sv[n] = s_lds[r * NM + ((n + r) & 63)];

        if (k < NM) {
            const int kk = k < 16 ? k : 16;   // dataset: k = 8
            u64 taken = 0ull;
            float mmax = 0.f, Z = 0.f;
            for (int i = 0; i < kk; ++i) {
                float m = -1.0e30f;
                int idx = 0;
#pragma unroll
                for (int n = 0; n < NM; ++n) {
                    const bool avail  = ((taken >> n) & 1ull) == 0ull;
                    const bool better = avail && (sv[n] > m);  // strict >: lowest idx ties
                    m   = better ? sv[n] : m;
                    idx = better ? n : idx;
                }
                taken |= (1ull << idx);
                if (i == 0) mmax = m;
                const float wv = expf(m - mmax);
                Z += wv;
                sel_i[r * 16 + i] = idx;
                sel_w[r * 16 + i] = wv;
            }
#pragma unroll
            for (int n = 0; n < NM; ++n) s_lds[r * NM + ((n + r) & 63)] = 0.f;
            for (int i = 0; i < kk; ++i) {
                const float wz = sel_w[r * 16 + i] / Z;
                sel_w[r * 16 + i] = wz;
                s_lds[r * NM + ((sel_i[r * 16 + i] + r) & 63)] = wz;
            }
        } else {
            float m = -1.0e30f;
#pragma unroll
            for (int n = 0; n < NM; ++n) m = sv[n] > m ? sv[n] : m;
            float Z = 0.f;
#pragma unroll
            for (int n = 0; n < NM; ++n) Z += expf(sv[n] - m);
#pragma unroll
            for (int n = 0; n < NM; ++n) s_lds[r * NM + ((n + r) & 63)] = expf(sv[n] - m) / Z;
        }
    }
    __syncthreads();

    // ---- attn stores (coalesced)
#pragma unroll
    for (int i = 0; i < (FR * NM) / 256; ++i) {    // 32 iters
        const int idx = i * 256 + t;
        const int r = idx >> 6, n = idx & 63;
        const int grow = row0 + r;
        if (grow < M) out_attn[(size_t)grow * NM + n] = s_lds[r * NM + ((n + r) & 63)];
    }

    // ---- retrieved (PV): wave w rows [32w, 32w+32); lane l = d-quad
    {
        const float4* mem4 = reinterpret_cast<const float4*>(mem);   // [NM][64]
        const int kk = k < 16 ? k : 16;
#pragma unroll 1
        for (int rr = 0; rr < FR / 4; ++rr) {
            const int r    = w * (FR / 4) + rr;
            const int grow = row0 + r;
            if (grow >= M) continue;
            float4 acc; acc.x = 0.f; acc.y = 0.f; acc.z = 0.f; acc.w = 0.f;
            if (k < NM) {
                for (int i = 0; i < kk; ++i) {
                    const int   mi = sel_i[r * 16 + i];      // uniform ds
                    const float wz = sel_w[r * 16 + i];
                    const float4 mv = mem4[mi * 64 + l];     // coalesced, L1-hot
                    acc.x = fmaf(wz, mv.x, acc.x);           // rank-ascending chain
                    acc.y = fmaf(wz, mv.y, acc.y);
                    acc.z = fmaf(wz, mv.z, acc.z);
                    acc.w = fmaf(wz, mv.w, acc.w);
                }
            } else {
                for (int n = 0; n < NM; ++n) {
                    const float wz = s_lds[r * NM + ((n + r) & 63)];
                    const float4 mv = mem4[n * 64 + l];
                    acc.x = fmaf(wz, mv.x, acc.x);           // n-ascending chain
                    acc.y = fmaf(wz, mv.y, acc.y);
                    acc.z = fmaf(wz, mv.z, acc.z);
                    acc.w = fmaf(wz, mv.w, acc.w);
                }
            }
            *reinterpret_cast<float4*>(&out_ret[(size_t)grow * DD + 4 * l]) = acc;
        }
    }
}

// ---------------------------------------------------------------------------
extern "C" void kernel_launch(void* const* d_in, const int* in_sizes, int n_in,
                              void* d_out, int out_size, void* d_ws, size_t ws_size,
                              hipStream_t stream) {
    const float* query      = (const float*)d_in[0];
    const float* memory     = (const float*)d_in[1];
    const float* importance = (const float*)d_in[2];
    const float* age        = (const float*)d_in[3];
    const float* Wq         = (const float*)d_in[4];
    const float* Wk         = (const float*)d_in[5];
    const int*   topk       = (const int*)d_in[6];

    const int M = in_sizes[0] / DD;   // B*S = 131072

    float* kT4  = (float*)d_ws;                      // 64 KB [og][n][4]
    float* bias = kT4 + (size_t)DD * NM;             // [NM]
    float* wqt  = bias + 64;                         // [DD][DD] = 256 KB
    float* wkt  = wqt + (size_t)DD * DD;             // [DD][DD] = 256 KB

    hipLaunchKernelGGL(prep_tr, dim3(DD, 2), dim3(DD), 0, stream,
                       Wq, Wk, wqt, wkt);
    hipLaunchKernelGGL(prep_kT, dim3(NM), dim3(DD), 0, stream,
                       memory, wkt, importance, age, kT4, bias);

    float* out_ret  = (float*)d_out;
    float* out_attn = out_ret + (size_t)M * DD;

    // raw scores staged through out_attn (33.5 MB); q never touches HBM.
    // fin3 reads its own score rows before overwriting with final attn.
    hipLaunchKernelGGL(qgemm_s, dim3((M + 31) / 32), dim3(ATHR), 0, stream,
                       query, (const float4*)wqt, (const float4*)kT4,
                       bias, out_attn, M);
    hipLaunchKernelGGL(fin3, dim3((M + FR - 1) / FR), dim3(256), 0, stream,
                       memory, topk, out_ret, out_attn, M);
}

// Round 23
// 397.133 us; speedup vs baseline: 1.0798x; 1.0798x over previous
//
#include <hip/hip_runtime.h>
#include <hip/hip_bf16.h>

#define DD 256      // feature dim
#define NM 64       // memory slots

typedef unsigned long long u64;
typedef float v2f __attribute__((ext_vector_type(2)));

struct v2x2 { v2f lo, hi; };
static __device__ __forceinline__ v2x2 splitf4(float4 f) {
    union { float4 a; v2x2 b; } u; u.a = f; return u.b;
}

// pk: acc(pair) += splat(src0 half) * c(pair).  Bit-identical to two fmaf.
#define PK_FMA_SPLATLO(acc, q2, c2) \
    asm("v_pk_fma_f32 %0, %1, %2, %0 op_sel:[0,0,0] op_sel_hi:[0,1,1]" \
        : "+v"(acc) : "v"(q2), "v"(c2))
#define PK_FMA_SPLATHI(acc, q2, c2) \
    asm("v_pk_fma_f32 %0, %1, %2, %0 op_sel:[1,0,0] op_sel_hi:[1,1,1]" \
        : "+v"(acc) : "v"(q2), "v"(c2))

// ---------------------------------------------------------------------------
// prep_tr: wt[d][o] = W[o][d] for Wq and Wk
// ---------------------------------------------------------------------------
__global__ __launch_bounds__(256) void prep_tr(
    const float* __restrict__ Wq, const float* __restrict__ Wk,
    float* __restrict__ wqt, float* __restrict__ wkt)
{
    const int o = blockIdx.x;
    const int d = threadIdx.x;
    if (blockIdx.y == 0) wqt[d * DD + o] = Wq[o * DD + d];
    else                 wkt[d * DD + o] = Wk[o * DD + d];
}

// ---------------------------------------------------------------------------
// prep_kT: kT4[(o>>2)*(NM*4) + n*4 + (o&3)] = k[n][o]   ([og][n][4] layout)
//   k[n][o] = sum_d mem[n][d]*Wk[o][d]  (fp32, d-ascending single-acc)
//   bias[n] = fl32(max(log(imp*0.99^age), -10))
// ---------------------------------------------------------------------------
__global__ __launch_bounds__(256) void prep_kT(
    const float* __restrict__ mem, const float* __restrict__ wkt,
    const float* __restrict__ imp, const float* __restrict__ age,
    float* __restrict__ kT4, float* __restrict__ bias)
{
    const int n = blockIdx.x;
    const int o = threadIdx.x;
    const float* mrow = mem + n * DD;
    float acc = 0.f;
    for (int d = 0; d < DD; ++d)
        acc = fmaf(mrow[d], wkt[d * DD + o], acc);
    kT4[(o >> 2) * (NM * 4) + n * 4 + (o & 3)] = acc;

    if (o == 0) {
        double eff = (double)imp[n] * pow(0.99, (double)age[n]);
        float b = (float)log(eff);
        if (!(b >= -10.0f)) b = -10.0f;
        bias[n] = b;
    }
}

// ---------------------------------------------------------------------------
// qgemm4: q = query @ Wq^T -> qout (= out_ret scratch). BYTE-IDENTICAL to
// R19's best (220 us; 6 structural variants all >= 220 -> accepted basin).
// ---------------------------------------------------------------------------
__global__ __launch_bounds__(256, 2) void qgemm4(
    const float* __restrict__ query,   // [M][DD]
    const float4* __restrict__ wqt4,   // [DD][NM]: wqt4[d*64+l] = WqT[d][4l..4l+3]
    float* __restrict__ qout,          // [M][DD]
    int M)
{
    __shared__ float q_lds[32 * DD];        // 32 KB query rows
    __shared__ float wq_lds[2][8 * 256];    // 16 KB dbuf: [d_local][o]

    const int t = threadIdx.x;
    const int l = t & 63;
    const int w = __builtin_amdgcn_readfirstlane((int)(t >> 6));  // 0..3
    const int row0 = blockIdx.x * 32;

    // stage 32 query rows (coalesced)
    {
        const float4* q4g = reinterpret_cast<const float4*>(query);
#pragma unroll
        for (int i = 0; i < 8; ++i) {
            const int idx = i * 256 + t;
            const int r = idx >> 6, c4 = idx & 63;
            int gr = row0 + r; if (gr > M - 1) gr = M - 1;
            *reinterpret_cast<float4*>(&q_lds[r * DD + c4 * 4]) =
                q4g[(size_t)gr * 64 + c4];
        }
    }
    // stage wqt chunk 0 (d = 0..7)
    {
        const float4 s0 = wqt4[t];
        const float4 s1 = wqt4[256 + t];
        reinterpret_cast<float4*>(wq_lds[0])[t]       = s0;
        reinterpret_cast<float4*>(wq_lds[0])[256 + t] = s1;
    }
    __syncthreads();

    v2f a01[8], a23[8];
#pragma unroll
    for (int rr = 0; rr < 8; ++rr) { a01[rr] = (v2f)(0.f); a23[rr] = (v2f)(0.f); }

    const float* qbase = &q_lds[(w * 8) * DD];

    for (int c = 0; c < 32; ++c) {
        const int cn = (c + 1) & 31;
        const float4 n0 = wqt4[cn * 512 + t];
        const float4 n1 = wqt4[cn * 512 + 256 + t];

        {
            const float4* wb = reinterpret_cast<const float4*>(wq_lds[c & 1]);
            float4 cw[8];
#pragma unroll
            for (int i = 0; i < 8; ++i) cw[i] = wb[i * 64 + l];
            const v2x2 c0 = splitf4(cw[0]), c1 = splitf4(cw[1]);
            const v2x2 c2 = splitf4(cw[2]), c3 = splitf4(cw[3]);
            const v2x2 c4 = splitf4(cw[4]), c5 = splitf4(cw[5]);
            const v2x2 c6 = splitf4(cw[6]), c7 = splitf4(cw[7]);
#pragma unroll
            for (int rr = 0; rr < 8; ++rr) {
                const float4 qqA = *reinterpret_cast<const float4*>(
                    qbase + rr * DD + c * 8);
                const float4 qqB = *reinterpret_cast<const float4*>(
                    qbase + rr * DD + c * 8 + 4);
                const v2x2 qA = splitf4(qqA);
                const v2x2 qB = splitf4(qqB);
                // d-ascending per chain (bit-identical):
                PK_FMA_SPLATLO(a01[rr], qA.lo, c0.lo);
                PK_FMA_SPLATLO(a23[rr], qA.lo, c0.hi);
                PK_FMA_SPLATHI(a01[rr], qA.lo, c1.lo);
                PK_FMA_SPLATHI(a23[rr], qA.lo, c1.hi);
                PK_FMA_SPLATLO(a01[rr], qA.hi, c2.lo);
                PK_FMA_SPLATLO(a23[rr], qA.hi, c2.hi);
                PK_FMA_SPLATHI(a01[rr], qA.hi, c3.lo);
                PK_FMA_SPLATHI(a23[rr], qA.hi, c3.hi);
                PK_FMA_SPLATLO(a01[rr], qB.lo, c4.lo);
                PK_FMA_SPLATLO(a23[rr], qB.lo, c4.hi);
                PK_FMA_SPLATHI(a01[rr], qB.lo, c5.lo);
                PK_FMA_SPLATHI(a23[rr], qB.lo, c5.hi);
                PK_FMA_SPLATLO(a01[rr], qB.hi, c6.lo);
                PK_FMA_SPLATLO(a23[rr], qB.hi, c6.hi);
                PK_FMA_SPLATHI(a01[rr], qB.hi, c7.lo);
                PK_FMA_SPLATHI(a23[rr], qB.hi, c7.hi);
            }
        }
        {
            float4* dst = reinterpret_cast<float4*>(wq_lds[(c + 1) & 1]);
            dst[t]       = n0;
            dst[256 + t] = n1;
        }
        __syncthreads();
    }

#pragma unroll
    for (int rr = 0; rr < 8; ++rr) {
        const int grow = row0 + w * 8 + rr;
        if (grow < M) {
            float4 v; v.x = a01[rr].x; v.y = a01[rr].y; v.z = a23[rr].x; v.w = a23[rr].y;
            *reinterpret_cast<float4*>(&qout[(size_t)grow * DD + 4 * l]) = v;
        }
    }
}

// ---------------------------------------------------------------------------
// scores_b: raw biased scores -> out_attn (scratch). R13-Phase-B mapping:
// lane = row (64 rows/block), wave w owns n in [8w,8w+8) -> kT wave-uniform
// s_load (scalar pipe, free); ONE swizzled per-lane ds_read_b128 per og.
// DS/VALU per og per wave: ~12 vs 64 cyc (scores_k's lane=n mapping was
// ~100 vs 64 -> DS-bound, the ~100us tail cost). Chain per (row,n):
// o-ascending fmaf — bit-identical to scores_k/R13 (both proven passing).
// 512 thr / 64 rows / 64 KB LDS (q swizzled; reused for rotated scores).
// ---------------------------------------------------------------------------
__global__ __launch_bounds__(512, 2) void scores_b(
    const float* __restrict__ qin,     // [M][DD] (= out_ret)
    const float4* __restrict__ kT44,   // [DD/4][NM]
    const float* __restrict__ bias,    // [NM]
    float* __restrict__ sout,          // [M][NM] (= out_attn, raw scores)
    int M)
{
    __shared__ float q_lds[64 * DD];   // 64 KB; first 16 KB reused for scores
    const int t = threadIdx.x;         // 0..511
    const int l = t & 63;
    const int w = __builtin_amdgcn_readfirstlane((int)(t >> 6));  // 0..7
    const int row0 = blockIdx.x * 64;

    // stage 64 q rows (coalesced read; swizzled write: f4-col c4 -> c4^r)
    {
        const float4* q4g = reinterpret_cast<const float4*>(qin);
#pragma unroll
        for (int i = 0; i < 8; ++i) {
            const int idx = i * 512 + t;          // wave w writes row i*8+w
            const int r = idx >> 6, c4 = idx & 63;
            int gr = row0 + r; if (gr > M - 1) gr = M - 1;
            *reinterpret_cast<float4*>(&q_lds[r * DD + ((c4 ^ r) & 63) * 4]) =
                q4g[(size_t)gr * 64 + c4];
        }
    }
    __syncthreads();

    // lane l = row l; wave w owns n in [8w, 8w+8)
    const int nb = w * 8;
    float sc[8];
#pragma unroll
    for (int j = 0; j < 8; ++j) sc[j] = 0.f;

    for (int og = 0; og < DD / 4; ++og) {
        const float4 q4 = *reinterpret_cast<const float4*>(
            &q_lds[l * DD + (((og ^ l) & 63) << 2)]);     // per-lane, conflict-free
        const float4* ktp = kT44 + og * NM + nb;          // wave-uniform -> s_load
#pragma unroll
        for (int j = 0; j < 8; ++j) {
            const float4 kt = ktp[j];
            float v = sc[j];
            v = fmaf(q4.x, kt.x, v);                      // o-ascending chain
            v = fmaf(q4.y, kt.y, v);
            v = fmaf(q4.z, kt.z, v);
            v = fmaf(q4.w, kt.w, v);
            sc[j] = v;
        }
    }
    __syncthreads();   // all q reads done -> reuse LDS for scores

    // rotated score tile: row l, col c stored at (c+l)&63 (conflict-free)
    float* s_tmp = q_lds;              // [64][64] = 16 KB
#pragma unroll
    for (int j = 0; j < 8; ++j)
        s_tmp[l * NM + ((nb + j + l) & 63)] = sc[j] * 0.0625f + bias[nb + j];
    __syncthreads();

    // coalesced stores
#pragma unroll
    for (int i = 0; i < 8; ++i) {
        const int idx = i * 512 + t;
        const int r = idx >> 6, n = idx & 63;
        const int grow = row0 + r;
        if (grow < M) sout[(size_t)grow * NM + n] = s_tmp[r * NM + ((n + r) & 63)];
    }
}

// ---------------------------------------------------------------------------
// fin3: raw scores (out_attn) -> topk (thread-per-row, 128 rows) -> final
// attn (overwrite out_attn, block-local) + retrieved (write out_ret fresh).
// Byte-identical to R19/R21's fin3.
// ---------------------------------------------------------------------------
#define FR 128    // rows per fin3 block
__global__ __launch_bounds__(256, 2) void fin3(
    const float* __restrict__ mem,     // [NM][DD]
    const int* __restrict__ topk_p,
    float* __restrict__ out_ret,       // [M][DD]
    float* __restrict__ out_attn,      // [M][NM] (raw scores in, attn out)
    int M)
{
    __shared__ float s_lds[FR * NM];   // 32 KB rotated scores
    __shared__ int   sel_i[FR * 16];   // 8 KB
    __shared__ float sel_w[FR * 16];   // 8 KB

    const int t = threadIdx.x;
    const int l = t & 63;
    const int w = __builtin_amdgcn_readfirstlane((int)(t >> 6));  // 0..3
    const int row0 = blockIdx.x * FR;
    const int k = *topk_p;

    // stage scores (coalesced read, rotated scatter: col c at (c+r)&63)
    {
#pragma unroll
        for (int i = 0; i < (FR * NM / 4) / 256; ++i) {    // 8 iters
            const int idx = i * 256 + t;                   // float4 index
            const int r = idx >> 4, c4 = idx & 15;
            int gr = row0 + r; if (gr > M - 1) gr = M - 1;
            const float4 v = *reinterpret_cast<const float4*>(
                &out_attn[(size_t)gr * NM + c4 * 4]);
            s_lds[r * NM + ((c4 * 4 + 0 + r) & 63)] = v.x;
            s_lds[r * NM + ((c4 * 4 + 1 + r) & 63)] = v.y;
            s_lds[r * NM + ((c4 * 4 + 2 + r) & 63)] = v.z;
            s_lds[r * NM + ((c4 * 4 + 3 + r) & 63)] = v.w;
        }
    }
    __syncthreads();

    // ---- per-row top-k: thread t handles row t (t < FR)
    if (t < FR) {
        const int r = t;
        float sv[NM];
#pragma unroll
        for (int n = 0; n < NM; ++n) sv[n] = s_lds[r * NM + ((n + r) & 63)];

        if (k < NM) {
            const int kk = k < 16 ? k : 16;   // dataset: k = 8
            u64 taken = 0ull;
            float mmax = 0.f, Z = 0.f;
            for (int i = 0; i < kk; ++i) {
                float m = -1.0e30f;
                int idx = 0;
#pragma unroll
                for (int n = 0; n < NM; ++n) {
                    const bool avail  = ((taken >> n) & 1ull) == 0ull;
                    const bool better = avail && (sv[n] > m);  // strict >: lowest idx ties
                    m   = better ? sv[n] : m;
                    idx = better ? n : idx;
                }
                taken |= (1ull << idx);
                if (i == 0) mmax = m;
                const float wv = expf(m - mmax);
                Z += wv;
                sel_i[r * 16 + i] = idx;
                sel_w[r * 16 + i] = wv;
            }
#pragma unroll
            for (int n = 0; n < NM; ++n) s_lds[r * NM + ((n + r) & 63)] = 0.f;
            for (int i = 0; i < kk; ++i) {
                const float wz = sel_w[r * 16 + i] / Z;
                sel_w[r * 16 + i] = wz;
                s_lds[r * NM + ((sel_i[r * 16 + i] + r) & 63)] = wz;
            }
        } else {
            float m = -1.0e30f;
#pragma unroll
            for (int n = 0; n < NM; ++n) m = sv[n] > m ? sv[n] : m;
            float Z = 0.f;
#pragma unroll
            for (int n = 0; n < NM; ++n) Z += expf(sv[n] - m);
#pragma unroll
            for (int n = 0; n < NM; ++n) s_lds[r * NM + ((n + r) & 63)] = expf(sv[n] - m) / Z;
        }
    }
    __syncthreads();

    // ---- attn stores (coalesced)
#pragma unroll
    for (int i = 0; i < (FR * NM) / 256; ++i) {    // 32 iters
        const int idx = i * 256 + t;
        const int r = idx >> 6, n = idx & 63;
        const int grow = row0 + r;
        if (grow < M) out_attn[(size_t)grow * NM + n] = s_lds[r * NM + ((n + r) & 63)];
    }

    // ---- retrieved (PV): wave w rows [32w, 32w+32); lane l = d-quad
    {
        const float4* mem4 = reinterpret_cast<const float4*>(mem);   // [NM][64]
        const int kk = k < 16 ? k : 16;
#pragma unroll 1
        for (int rr = 0; rr < FR / 4; ++rr) {
            const int r    = w * (FR / 4) + rr;
            const int grow = row0 + r;
            if (grow >= M) continue;
            float4 acc; acc.x = 0.f; acc.y = 0.f; acc.z = 0.f; acc.w = 0.f;
            if (k < NM) {
                for (int i = 0; i < kk; ++i) {
                    const int   mi = sel_i[r * 16 + i];      // uniform ds
                    const float wz = sel_w[r * 16 + i];
                    const float4 mv = mem4[mi * 64 + l];     // coalesced, L1-hot
                    acc.x = fmaf(wz, mv.x, acc.x);           // rank-ascending chain
                    acc.y = fmaf(wz, mv.y, acc.y);
                    acc.z = fmaf(wz, mv.z, acc.z);
                    acc.w = fmaf(wz, mv.w, acc.w);
                }
            } else {
                for (int n = 0; n < NM; ++n) {
                    const float wz = s_lds[r * NM + ((n + r) & 63)];
                    const float4 mv = mem4[n * 64 + l];
                    acc.x = fmaf(wz, mv.x, acc.x);           // n-ascending chain
                    acc.y = fmaf(wz, mv.y, acc.y);
                    acc.z = fmaf(wz, mv.z, acc.z);
                    acc.w = fmaf(wz, mv.w, acc.w);
                }
            }
            *reinterpret_cast<float4*>(&out_ret[(size_t)grow * DD + 4 * l]) = acc;
        }
    }
}

// ---------------------------------------------------------------------------
extern "C" void kernel_launch(void* const* d_in, const int* in_sizes, int n_in,
                              void* d_out, int out_size, void* d_ws, size_t ws_size,
                              hipStream_t stream) {
    const float* query      = (const float*)d_in[0];
    const float* memory     = (const float*)d_in[1];
    const float* importance = (const float*)d_in[2];
    const float* age        = (const float*)d_in[3];
    const float* Wq         = (const float*)d_in[4];
    const float* Wk         = (const float*)d_in[5];
    const int*   topk       = (const int*)d_in[6];

    const int M = in_sizes[0] / DD;   // B*S = 131072

    float* kT4  = (float*)d_ws;                      // 64 KB [og][n][4]
    float* bias = kT4 + (size_t)DD * NM;             // [NM]
    float* wqt  = bias + 64;                         // [DD][DD] = 256 KB
    float* wkt  = wqt + (size_t)DD * DD;             // [DD][DD] = 256 KB

    hipLaunchKernelGGL(prep_tr, dim3(DD, 2), dim3(DD), 0, stream,
                       Wq, Wk, wqt, wkt);
    hipLaunchKernelGGL(prep_kT, dim3(NM), dim3(DD), 0, stream,
                       memory, wkt, importance, age, kT4, bias);

    float* out_ret  = (float*)d_out;
    float* out_attn = out_ret + (size_t)M * DD;

    // q staged through out_ret; raw scores through out_attn; fin3 reads its
    // own rows of both before overwriting with final outputs.
    hipLaunchKernelGGL(qgemm4, dim3((M + 31) / 32), dim3(256), 0, stream,
                       query, (const float4*)wqt, out_ret, M);
    hipLaunchKernelGGL(scores_b, dim3((M + 63) / 64), dim3(512), 0, stream,
                       out_ret, (const float4*)kT4, bias, out_attn, M);
    hipLaunchKernelGGL(fin3, dim3((M + FR - 1) / FR), dim3(256), 0, stream,
                       memory, topk, out_ret, out_attn, M);
}